// Round 15
// baseline (293.735 us; speedup 1.0000x reference)
//
#include <hip/hip_runtime.h>
#include <hip/hip_bf16.h>
#include <stdint.h>

// RoPE attention, B=2 S=2048 D=2048 H=16 hd=128.
// conv(all f32->bf16 + rope table) -> merged QKV GEMM (128x128, BK=64,
//   2-slot counted-vmcnt pipeline, swizzled LDS; Q plain | K rope | V->Vt)
// -> flash attention (8-wave, KVBLK=128, counted-vmcnt pipeline, in-register
//    P, XCD swizzle, log2 softmax, defer-max) -> output GEMM (f32 out).
//
// Pipeline pattern (T4): prefetch distance 2; per step:
//   s_waitcnt vmcnt(N_inflight); s_barrier;   // tile t ready block-wide
//   COMPUTE(slot t&1);
//   s_barrier;  STAGE(slot t&1, tile t+2);    // overwrite after all reads
// Loads for tile t+2 land during iteration t+1 => no exposed latency.

typedef __attribute__((ext_vector_type(4))) float f32x4;
typedef __attribute__((ext_vector_type(8))) short bf16x8;

typedef __attribute__((address_space(3))) unsigned int lds_u32;
typedef __attribute__((address_space(1))) const unsigned int gbl_u32;

__device__ __forceinline__ void async16(const void* g, void* l) {
  __builtin_amdgcn_global_load_lds((gbl_u32*)g, (lds_u32*)l, 16, 0, 0);
}

__device__ __forceinline__ float bf_to_f(unsigned short u) {
  union { unsigned int i; float f; } v; v.i = ((unsigned int)u) << 16; return v.f;
}
__device__ __forceinline__ unsigned short f_to_bf(float f) {
  union { float f; unsigned int i; } v; v.f = f;
  unsigned int r = v.i + 0x7FFFu + ((v.i >> 16) & 1u);  // RNE
  return (unsigned short)(r >> 16);
}
__device__ __forceinline__ unsigned int cvt_pk_bf16(float lo, float hi) {
  unsigned int r;
  asm("v_cvt_pk_bf16_f32 %0, %1, %2" : "=v"(r) : "v"(lo), "v"(hi));
  return r;
}

#define B_ 2
#define S_ 2048
#define D_ 2048
#define H_ 16
#define HD_ 128
#define KVB 128

// ---------------- fused f32->bf16 convert (x + 4 weights) + rope table ------
__global__ __launch_bounds__(256) void conv_all(const float* __restrict__ x,
                                                const float* __restrict__ wq,
                                                const float* __restrict__ wk,
                                                const float* __restrict__ wv,
                                                const float* __restrict__ wo,
                                                unsigned short* __restrict__ xb,
                                                unsigned short* __restrict__ wb,
                                                float* __restrict__ cosT,
                                                float* __restrict__ sinT) {
  int i = blockIdx.x * 256 + threadIdx.x;  // [0, 6291456 + 131072)
  if (i >= 6291456) {
    int j = i - 6291456;  // rope table entry, [0, 131072)
    int s = j >> 6, jj = j & 63;
    float inv = powf(10000.0f, -(float)(2 * jj) * (1.0f / 128.0f));
    float ang = (float)s * inv;
    float sv, cv;
    sincosf(ang, &sv, &cv);
    cosT[j] = cv;
    sinT[j] = sv;
    return;
  }
  const float* s;
  unsigned short* d;
  int off;
  if (i < 2097152) {
    s = x; d = xb; off = i;
  } else {
    int j = i - 2097152;
    int t = j >> 20;
    off = j & 1048575;
    s = (t == 0) ? wq : (t == 1) ? wk : (t == 2) ? wv : wo;
    d = wb + (size_t)t * 4194304;
  }
  float4 v = ((const float4*)s)[off];
  uint2 o;
  o.x = (unsigned int)f_to_bf(v.x) | ((unsigned int)f_to_bf(v.y) << 16);
  o.y = (unsigned int)f_to_bf(v.z) | ((unsigned int)f_to_bf(v.w) << 16);
  ((uint2*)d)[off] = o;
}

// ---------------- merged QKV GEMM (128x128, BK=64, counted-vmcnt dbuf) ------
// C = x[4096,2048] * W[6144,2048]^T, W = [wq; wk; wv] contiguous.
// grid (32, 48): bn>>4 selects sector 0=Q(plain), 1=K(rope), 2=V(->Vt).
// 128-B LDS rows, read swizzle byte^=((row&7)<<4); pre-swizzled gload source.
__global__ __launch_bounds__(256, 2) void qkv_gemm(const unsigned short* __restrict__ A,
                                                   const unsigned short* __restrict__ W,
                                                   unsigned short* __restrict__ Qb,
                                                   unsigned short* __restrict__ Kb,
                                                   unsigned short* __restrict__ Vtb,
                                                   const float* __restrict__ cosT,
                                                   const float* __restrict__ sinT) {
  __shared__ unsigned short sA[2][128 * 64];  // 2 x 16 KB
  __shared__ unsigned short sB[2][128 * 64];  // 2 x 16 KB
  const int K = 2048, N = 2048;
  const int tid = threadIdx.x;
  const int l = tid & 63, wv = tid >> 6;
  const int lane15 = l & 15, lhi = l >> 4;
  const int wm = wv >> 1, wn = wv & 1;
  const int bm = blockIdx.x, bn = blockIdx.y;
  const int sector = bn >> 4, bnl = bn & 15;

  // staging: per thread 4 A-chunks + 4 B-chunks of 16B per tile (8 loads)
  const int srow = tid >> 3;                 // 0..31 -> x4 rows of 32
  const int colD = (tid & 7) << 4;
  const unsigned short* aSrc[4];
  const unsigned short* bSrc[4];
  unsigned int lofs[4];
#pragma unroll
  for (int i = 0; i < 4; i++) {
    int row = i * 32 + srow;
    int cS = colD ^ ((row & 7) << 4);
    aSrc[i] = A + (size_t)(bm * 128 + row) * K + (cS >> 1);
    bSrc[i] = W + (size_t)(bn * 128 + row) * K + (cS >> 1);
    lofs[i] = row * 128 + colD;
  }

  f32x4 acc[4][4];
  const f32x4 zero = {0.f, 0.f, 0.f, 0.f};
#pragma unroll
  for (int i = 0; i < 4; i++)
#pragma unroll
    for (int j = 0; j < 4; j++) acc[i][j] = zero;

  auto stage = [&](int slot) {
#pragma unroll
    for (int i = 0; i < 4; i++) {
      async16(aSrc[i], (char*)&sA[slot][0] + lofs[i]); aSrc[i] += 64;
      async16(bSrc[i], (char*)&sB[slot][0] + lofs[i]); bSrc[i] += 64;
    }
  };
  auto compute = [&](int slot) {
    const char* sAc = (const char*)&sA[slot][0];
    const char* sBc = (const char*)&sB[slot][0];
#pragma unroll
    for (int h = 0; h < 2; h++) {
      bf16x8 af[4], bfr[4];
#pragma unroll
      for (int i = 0; i < 4; i++) {
        int row = wm * 64 + i * 16 + lane15;
        af[i] = *(const bf16x8*)(sAc + row * 128 +
                                 ((h * 64 + lhi * 16) ^ ((row & 7) << 4)));
      }
#pragma unroll
      for (int j = 0; j < 4; j++) {
        int row = wn * 64 + j * 16 + lane15;
        bfr[j] = *(const bf16x8*)(sBc + row * 128 +
                                  ((h * 64 + lhi * 16) ^ ((row & 7) << 4)));
      }
      __builtin_amdgcn_s_setprio(1);
#pragma unroll
      for (int i = 0; i < 4; i++)
#pragma unroll
        for (int j = 0; j < 4; j++)
          acc[i][j] = __builtin_amdgcn_mfma_f32_16x16x32_bf16(af[i], bfr[j], acc[i][j], 0, 0, 0);
      __builtin_amdgcn_s_setprio(0);
    }
  };

  // prologue: stage tiles 0,1 (16 loads in flight)
  stage(0);
  stage(1);

  for (int t = 0; t < 30; ++t) {
    asm volatile("s_waitcnt vmcnt(8)" ::: "memory");  // tile t landed
    __builtin_amdgcn_s_barrier();
    compute(t & 1);
    __builtin_amdgcn_s_barrier();  // all waves done reading slot t&1
    stage(t & 1);                  // tile t+2 -> slot t&1
  }
  asm volatile("s_waitcnt vmcnt(8)" ::: "memory");
  __builtin_amdgcn_s_barrier();
  compute(0);  // t = 30
  asm volatile("s_waitcnt vmcnt(0)" ::: "memory");
  __builtin_amdgcn_s_barrier();
  compute(1);  // t = 31

  // epilogue: C/D layout col=lane&15, row=(lane>>4)*4+r
#pragma unroll
  for (int i = 0; i < 4; i++) {
    int m0 = bm * 128 + wm * 64 + i * 16 + lhi * 4;
#pragma unroll
    for (int j = 0; j < 4; j++) {
      int n = bnl * 128 + wn * 64 + j * 16 + lane15;
      if (sector == 0) {
#pragma unroll
        for (int r = 0; r < 4; r++) Qb[(size_t)(m0 + r) * N + n] = f_to_bf(acc[i][j][r]);
      } else if (sector == 1) {  // K + rope
        int s0 = m0 & (S_ - 1);
        int jp = (n & (HD_ - 1)) >> 1;
        int odd = n & 1;
#pragma unroll
        for (int r = 0; r < 4; r++) {
          float own = acc[i][j][r];
          float prt = __shfl_xor(own, 1);
          float c = cosT[(s0 + r) * 64 + jp];
          float sn = sinT[(s0 + r) * 64 + jp];
          float outv = odd ? fmaf(prt, sn, own * c) : own * c - prt * sn;
          Kb[(size_t)(m0 + r) * N + n] = f_to_bf(outv);
        }
      } else {  // V -> Vt[b*2048 + n][s], 4 consecutive s packed
        int s0 = m0 & (S_ - 1);
        size_t row = (size_t)((m0 >> 11) * D_ + n);
        uint2 st;
        st.x = (unsigned int)f_to_bf(acc[i][j][0]) | ((unsigned int)f_to_bf(acc[i][j][1]) << 16);
        st.y = (unsigned int)f_to_bf(acc[i][j][2]) | ((unsigned int)f_to_bf(acc[i][j][3]) << 16);
        *(uint2*)(Vtb + row * S_ + s0) = st;
      }
    }
  }
}

// ---------------- output GEMM (same counted-vmcnt geometry): f32 out --------
__global__ __launch_bounds__(256, 2) void gemm_out(const unsigned short* __restrict__ A,
                                                   const unsigned short* __restrict__ Bm,
                                                   float* __restrict__ Cf) {
  __shared__ unsigned short sA[2][128 * 64];
  __shared__ unsigned short sB[2][128 * 64];
  const int K = 2048, N = 2048;
  const int tid = threadIdx.x;
  const int l = tid & 63, wv = tid >> 6;
  const int lane15 = l & 15, lhi = l >> 4;
  const int wm = wv >> 1, wn = wv & 1;
  const int bm = blockIdx.x, bn = blockIdx.y;

  const int srow = tid >> 3;
  const int colD = (tid & 7) << 4;
  const unsigned short* aSrc[4];
  const unsigned short* bSrc[4];
  unsigned int lofs[4];
#pragma unroll
  for (int i = 0; i < 4; i++) {
    int row = i * 32 + srow;
    int cS = colD ^ ((row & 7) << 4);
    aSrc[i] = A + (size_t)(bm * 128 + row) * K + (cS >> 1);
    bSrc[i] = Bm + (size_t)(bn * 128 + row) * K + (cS >> 1);
    lofs[i] = row * 128 + colD;
  }

  f32x4 acc[4][4];
  const f32x4 zero = {0.f, 0.f, 0.f, 0.f};
#pragma unroll
  for (int i = 0; i < 4; i++)
#pragma unroll
    for (int j = 0; j < 4; j++) acc[i][j] = zero;

  auto stage = [&](int slot) {
#pragma unroll
    for (int i = 0; i < 4; i++) {
      async16(aSrc[i], (char*)&sA[slot][0] + lofs[i]); aSrc[i] += 64;
      async16(bSrc[i], (char*)&sB[slot][0] + lofs[i]); bSrc[i] += 64;
    }
  };
  auto compute = [&](int slot) {
    const char* sAc = (const char*)&sA[slot][0];
    const char* sBc = (const char*)&sB[slot][0];
#pragma unroll
    for (int h = 0; h < 2; h++) {
      bf16x8 af[4], bfr[4];
#pragma unroll
      for (int i = 0; i < 4; i++) {
        int row = wm * 64 + i * 16 + lane15;
        af[i] = *(const bf16x8*)(sAc + row * 128 +
                                 ((h * 64 + lhi * 16) ^ ((row & 7) << 4)));
      }
#pragma unroll
      for (int j = 0; j < 4; j++) {
        int row = wn * 64 + j * 16 + lane15;
        bfr[j] = *(const bf16x8*)(sBc + row * 128 +
                                  ((h * 64 + lhi * 16) ^ ((row & 7) << 4)));
      }
      __builtin_amdgcn_s_setprio(1);
#pragma unroll
      for (int i = 0; i < 4; i++)
#pragma unroll
        for (int j = 0; j < 4; j++)
          acc[i][j] = __builtin_amdgcn_mfma_f32_16x16x32_bf16(af[i], bfr[j], acc[i][j], 0, 0, 0);
      __builtin_amdgcn_s_setprio(0);
    }
  };

  stage(0);
  stage(1);
  for (int t = 0; t < 30; ++t) {
    asm volatile("s_waitcnt vmcnt(8)" ::: "memory");
    __builtin_amdgcn_s_barrier();
    compute(t & 1);
    __builtin_amdgcn_s_barrier();
    stage(t & 1);
  }
  asm volatile("s_waitcnt vmcnt(8)" ::: "memory");
  __builtin_amdgcn_s_barrier();
  compute(0);
  asm volatile("s_waitcnt vmcnt(0)" ::: "memory");
  __builtin_amdgcn_s_barrier();
  compute(1);

#pragma unroll
  for (int i = 0; i < 4; i++) {
    int m0 = bm * 128 + wm * 64 + i * 16 + lhi * 4;
#pragma unroll
    for (int j = 0; j < 4; j++) {
      int n = bn * 128 + wn * 64 + j * 16 + lane15;
#pragma unroll
      for (int r = 0; r < 4; r++) Cf[(size_t)(m0 + r) * N + n] = acc[i][j][r];
    }
  }
}

// ---------------- flash attention (counted-vmcnt pipeline) ------------------
// grid (8, 32): 256 blocks of 512 threads = 1 block/CU.
// XCD swizzle: blockIdx.x owns bh in [bx*4, bx*4+4) (4 MB KV = its L2).
// KVBLK=128 (16 k-tiles); 8 waves x QBLK=32; waves 0-3 stage K, 4-7 stage V.
// Scores in log2-units; P in registers (cvt_pk + permlane swaps).
__global__ __launch_bounds__(512, 2) void attn_kernel(const unsigned short* __restrict__ Q,
                                                      const unsigned short* __restrict__ K,
                                                      const unsigned short* __restrict__ Vt,
                                                      unsigned short* __restrict__ ctx,
                                                      const float* __restrict__ cosT,
                                                      const float* __restrict__ sinT) {
  __shared__ unsigned short sK[2][KVB * 128];  // [k][d], 256B rows, 32 KB each
  __shared__ unsigned short sV[2][128 * KVB];  // [d][s], 256B rows, 32 KB each
  const int tid = threadIdx.x, l = tid & 63, w = tid >> 6;
  const int lane15 = l & 15, lhi = l >> 4;
  const int bh = blockIdx.x * 4 + (blockIdx.y >> 3);
  const int qt = blockIdx.y & 7;
  const int b = bh >> 4, h = bh & 15;
  const int q0 = qt * 256;
  const unsigned short* Kg = K + ((size_t)(b * S_)) * D_ + h * HD_;
  const unsigned short* Vg = Vt + ((size_t)bh * HD_) * S_;
  const float qscale = 0.08838834764831845f * 1.44269504f;  // scale * log2(e)
  const float THR = 11.5415603f;                            // 8 * log2(e)

  const unsigned short* gp[8];
  unsigned int lofs[8];
  size_t gstep;
  if (w < 4) {
#pragma unroll
    for (int i = 0; i < 8; i++) {
      int row = w * 32 + i * 4 + (l >> 4);
      int colD = (l & 15) << 4;
      int colS = colD ^ ((row & 7) << 4);
      gp[i] = Kg + (size_t)row * D_ + (colS >> 1);
      lofs[i] = row * 256 + colD;
    }
    gstep = (size_t)KVB * D_;
  } else {
#pragma unroll
    for (int i = 0; i < 8; i++) {
      int row = (w - 4) * 32 + i * 4 + (l >> 4);
      int colD = (l & 15) << 4;
      int colS = colD ^ ((row & 7) << 4);
      gp[i] = Vg + (size_t)row * S_ + (colS >> 1);
      lofs[i] = row * 256 + colD;
    }
    gstep = KVB;
  }

  // Q load + RoPE + qscale (once per block; pairs in-lane)
  bf16x8 qf[2][4];
#pragma unroll
  for (int s = 0; s < 2; s++) {
    int s_q = q0 + w * 32 + s * 16 + lane15;
    const unsigned short* Qrow = Q + ((size_t)(b * S_ + s_q)) * D_ + h * HD_;
#pragma unroll
    for (int kc = 0; kc < 4; kc++) {
      int d0 = kc * 32 + lhi * 8;
      uint4 raw = *(const uint4*)(Qrow + d0);
      float4 cv = *(const float4*)(cosT + (size_t)s_q * 64 + (d0 >> 1));
      float4 sv = *(const float4*)(sinT + (size_t)s_q * 64 + (d0 >> 1));
      unsigned int u[4] = {raw.x, raw.y, raw.z, raw.w};
      float cc[4] = {cv.x, cv.y, cv.z, cv.w};
      float ss[4] = {sv.x, sv.y, sv.z, sv.w};
      unsigned int o[4];
#pragma unroll
      for (int p = 0; p < 4; p++) {
        float re = bf_to_f((unsigned short)(u[p] & 0xffffu));
        float im = bf_to_f((unsigned short)(u[p] >> 16));
        float orr = (re * cc[p] - im * ss[p]) * qscale;
        float oi = (re * ss[p] + im * cc[p]) * qscale;
        o[p] = (unsigned int)f_to_bf(orr) | ((unsigned int)f_to_bf(oi) << 16);
      }
      union { uint4 u4; bf16x8 v; } cvt;
      cvt.u4.x = o[0]; cvt.u4.y = o[1]; cvt.u4.z = o[2]; cvt.u4.w = o[3];
      qf[s][kc] = cvt.v;
    }
  }

  float mrun[2] = {-1e30f, -1e30f}, lrun[2] = {0.f, 0.f};
  const f32x4 zero = {0.f, 0.f, 0.f, 0.f};
  f32x4 oacc[2][8];
#pragma unroll
  for (int s = 0; s < 2; s++)
#pragma unroll
    for (int nf = 0; nf < 8; nf++) oacc[s][nf] = zero;

  auto stage = [&](int slot) {
    char* base = (w < 4) ? (char*)&sK[slot][0] : (char*)&sV[slot][0];
#pragma unroll
    for (int i = 0; i < 8; i++) { async16(gp[i], base + lofs[i]); gp[i] += gstep; }
  };

  auto compute = [&](int slot) {
    const unsigned short* sKc = sK[slot];
    const unsigned short* sVc = sV[slot];

    f32x4 sacc[2][8];
#pragma unroll
    for (int s = 0; s < 2; s++)
#pragma unroll
      for (int n = 0; n < 8; n++) sacc[s][n] = zero;
    __builtin_amdgcn_s_setprio(1);
#pragma unroll
    for (int n = 0; n < 8; n++) {
      int row = n * 16 + lane15;
#pragma unroll
      for (int kc = 0; kc < 4; kc++) {
        bf16x8 kf = *(const bf16x8*)((const char*)sKc + row * 256 +
                                     ((kc * 64 + lhi * 16) ^ ((row & 7) << 4)));
        sacc[0][n] = __builtin_amdgcn_mfma_f32_16x16x32_bf16(kf, qf[0][kc], sacc[0][n], 0, 0, 0);
        sacc[1][n] = __builtin_amdgcn_mfma_f32_16x16x32_bf16(kf, qf[1][kc], sacc[1][n], 0, 0, 0);
      }
    }
    __builtin_amdgcn_s_setprio(0);

    float pmax[2];
#pragma unroll
    for (int s = 0; s < 2; s++) {
      float mn[8];
#pragma unroll
      for (int n = 0; n < 8; n++)
        mn[n] = fmaxf(fmaxf(sacc[s][n][0], sacc[s][n][1]), fmaxf(sacc[s][n][2], sacc[s][n][3]));
      float pm = fmaxf(fmaxf(fmaxf(mn[0], mn[1]), fmaxf(mn[2], mn[3])),
                       fmaxf(fmaxf(mn[4], mn[5]), fmaxf(mn[6], mn[7])));
      pm = fmaxf(pm, __shfl_xor(pm, 16));
      pm = fmaxf(pm, __shfl_xor(pm, 32));
      pmax[s] = pm;
    }
    if (!__all(fmaxf(pmax[0] - mrun[0], pmax[1] - mrun[1]) <= THR)) {
#pragma unroll
      for (int s = 0; s < 2; s++) {
        float mnew = fmaxf(mrun[s], pmax[s]);
        float alpha = exp2f(mrun[s] - mnew);
        lrun[s] *= alpha;
        float af[4];
#pragma unroll
        for (int r = 0; r < 4; r++) af[r] = __shfl(alpha, lhi * 4 + r);
#pragma unroll
        for (int nf = 0; nf < 8; nf++)
#pragma unroll
          for (int r = 0; r < 4; r++) oacc[s][nf][r] *= af[r];
        mrun[s] = mnew;
      }
    }
    bf16x8 paS[2][4];
#pragma unroll
    for (int s = 0; s < 2; s++) {
      float rs = 0.f;
      unsigned int wlo[8], whi[8];
#pragma unroll
      for (int n = 0; n < 8; n++) {
        float p0 = exp2f(sacc[s][n][0] - mrun[s]);
        float p1 = exp2f(sacc[s][n][1] - mrun[s]);
        float p2 = exp2f(sacc[s][n][2] - mrun[s]);
        float p3 = exp2f(sacc[s][n][3] - mrun[s]);
        rs += (p0 + p1) + (p2 + p3);
        wlo[n] = cvt_pk_bf16(p0, p1);
        whi[n] = cvt_pk_bf16(p2, p3);
      }
      rs += __shfl_xor(rs, 16);
      rs += __shfl_xor(rs, 32);
      lrun[s] += rs;
#pragma unroll
      for (int kc = 0; kc < 4; kc++) {
        unsigned int A = wlo[2 * kc], Bw = whi[2 * kc];
        unsigned int C = wlo[2 * kc + 1], Dw = whi[2 * kc + 1];
        asm("v_permlane32_swap_b32 %0, %1" : "+v"(A), "+v"(C));
        asm("v_permlane16_swap_b32 %0, %1" : "+v"(A), "+v"(C));
        asm("v_permlane32_swap_b32 %0, %1" : "+v"(Bw), "+v"(Dw));
        asm("v_permlane16_swap_b32 %0, %1" : "+v"(Bw), "+v"(Dw));
        union { uint4 u4; bf16x8 v; } pk;
        pk.u4.x = A; pk.u4.y = Bw; pk.u4.z = C; pk.u4.w = Dw;
        paS[s][kc] = pk.v;
      }
    }

    __builtin_amdgcn_s_setprio(1);
#pragma unroll
    for (int nf = 0; nf < 8; nf++) {
      int row = nf * 16 + lane15;
#pragma unroll
      for (int kc = 0; kc < 4; kc++) {
        bf16x8 vf = *(const bf16x8*)((const char*)sVc + row * 256 +
                                     ((kc * 64 + lhi * 16) ^ ((row & 7) << 4)));
        oacc[0][nf] = __builtin_amdgcn_mfma_f32_16x16x32_bf16(paS[0][kc], vf, oacc[0][nf], 0, 0, 0);
        oacc[1][nf] = __builtin_amdgcn_mfma_f32_16x16x32_bf16(paS[1][kc], vf, oacc[1][nf], 0, 0, 0);
      }
    }
    __builtin_amdgcn_s_setprio(0);
  };

  // prologue: tiles 0,1 -> slots 0,1 (16 loads in flight per wave)
  stage(0);
  stage(1);

  for (int t = 0; t < 14; ++t) {
    asm volatile("s_waitcnt vmcnt(8)" ::: "memory");  // tile t landed
    __builtin_amdgcn_s_barrier();
    compute(t & 1);
    __builtin_amdgcn_s_barrier();  // all waves done reading slot t&1
    stage(t & 1);                  // tile t+2 -> slot t&1
  }
  asm volatile("s_waitcnt vmcnt(8)" ::: "memory");
  __builtin_amdgcn_s_barrier();
  compute(0);  // t = 14
  asm volatile("s_waitcnt vmcnt(0)" ::: "memory");
  __builtin_amdgcn_s_barrier();
  compute(1);  // t = 15

  // epilogue: oacc[s] rows q=lhi*4+r, cols d=nf*16+lane15
#pragma unroll
  for (int s = 0; s < 2; s++) {
    float inv = 1.0f / lrun[s];
    float invr[4];
#pragma unroll
    for (int r = 0; r < 4; r++) invr[r] = __shfl(inv, lhi * 4 + r);
    unsigned short* Og = ctx + ((size_t)(b * S_ + q0 + w * 32 + s * 16)) * D_ + h * HD_;
#pragma unroll
    for (int r = 0; r < 4; r++) {
      int qrow = lhi * 4 + r;
#pragma unroll
      for (int nf = 0; nf < 8; nf++)
        Og[(size_t)qrow * D_ + nf * 16 + lane15] = f_to_bf(oacc[s][nf][r] * invr[r]);
    }
  }
}

// ---------------- launcher ----------------
extern "C" void kernel_launch(void* const* d_in, const int* in_sizes, int n_in,
                              void* d_out, int out_size, void* d_ws, size_t ws_size,
                              hipStream_t stream) {
  (void)in_sizes; (void)n_in; (void)out_size; (void)ws_size;
  const float* x = (const float*)d_in[0];
  const float* wq = (const float*)d_in[1];
  const float* wk = (const float*)d_in[2];
  const float* wv = (const float*)d_in[3];
  const float* wo = (const float*)d_in[4];
  float* out = (float*)d_out;

  char* ws = (char*)d_ws;
  const size_t MB = 1024 * 1024;
  unsigned short* xb  = (unsigned short*)(ws + 0 * MB);    // 16 MB; later aliased as ctx
  unsigned short* wqb = (unsigned short*)(ws + 16 * MB);   // W[6144+2048][2048] contiguous
  unsigned short* wob = (unsigned short*)(ws + 40 * MB);
  unsigned short* Qb  = (unsigned short*)(ws + 48 * MB);   // 16 MB
  unsigned short* Kb  = (unsigned short*)(ws + 64 * MB);   // 16 MB
  unsigned short* Vtb = (unsigned short*)(ws + 80 * MB);   // 16 MB
  float* cosT = (float*)(ws + 96 * MB);                    // 0.5 MB
  float* sinT = (float*)(ws + 96 * MB + 524288);           // 0.5 MB
  unsigned short* ctxb = xb;  // x_bf16 dead after QKV GEMM

  const int M = B_ * S_;  // 4096

  conv_all<<<25088, 256, 0, stream>>>(x, wq, wk, wv, wo, xb, wqb, cosT, sinT);

  qkv_gemm<<<dim3(M / 128, 48), 256, 0, stream>>>(xb, wqb, Qb, Kb, Vtb, cosT, sinT);

  attn_kernel<<<dim3(8, 32), 512, 0, stream>>>(Qb, Kb, Vtb, ctxb, cosT, sinT);

  gemm_out<<<dim3(M / 128, D_ / 128), 256, 0, stream>>>(ctxb, wob, out);
}

// Round 16
// 262.880 us; speedup vs baseline: 1.1174x; 1.1174x over previous
//
#include <hip/hip_runtime.h>
#include <hip/hip_bf16.h>
#include <stdint.h>

// RoPE attention, B=2 S=2048 D=2048 H=16 hd=128.
// conv(all f32->bf16 + rope table) -> merged QKV GEMM (128x128, BK=64,
//   counted-vmcnt 2-slot pipeline, swizzled LDS; Q plain | K rope | V->Vt)
// -> flash attention (8-wave, KVBLK=128, syncthreads-dbuf staging,
//    in-register P, XCD swizzle, log2 softmax, defer-max)
// -> output GEMM (counted-vmcnt; f32 out).

typedef __attribute__((ext_vector_type(4))) float f32x4;
typedef __attribute__((ext_vector_type(8))) short bf16x8;

typedef __attribute__((address_space(3))) unsigned int lds_u32;
typedef __attribute__((address_space(1))) const unsigned int gbl_u32;

__device__ __forceinline__ void async16(const void* g, void* l) {
  __builtin_amdgcn_global_load_lds((gbl_u32*)g, (lds_u32*)l, 16, 0, 0);
}

__device__ __forceinline__ float bf_to_f(unsigned short u) {
  union { unsigned int i; float f; } v; v.i = ((unsigned int)u) << 16; return v.f;
}
__device__ __forceinline__ unsigned short f_to_bf(float f) {
  union { float f; unsigned int i; } v; v.f = f;
  unsigned int r = v.i + 0x7FFFu + ((v.i >> 16) & 1u);  // RNE
  return (unsigned short)(r >> 16);
}
__device__ __forceinline__ unsigned int cvt_pk_bf16(float lo, float hi) {
  unsigned int r;
  asm("v_cvt_pk_bf16_f32 %0, %1, %2" : "=v"(r) : "v"(lo), "v"(hi));
  return r;
}

#define B_ 2
#define S_ 2048
#define D_ 2048
#define H_ 16
#define HD_ 128
#define KVB 128

// ---------------- fused f32->bf16 convert (x + 4 weights) + rope table ------
__global__ __launch_bounds__(256) void conv_all(const float* __restrict__ x,
                                                const float* __restrict__ wq,
                                                const float* __restrict__ wk,
                                                const float* __restrict__ wv,
                                                const float* __restrict__ wo,
                                                unsigned short* __restrict__ xb,
                                                unsigned short* __restrict__ wb,
                                                float* __restrict__ cosT,
                                                float* __restrict__ sinT) {
  int i = blockIdx.x * 256 + threadIdx.x;  // [0, 6291456 + 131072)
  if (i >= 6291456) {
    int j = i - 6291456;  // rope table entry, [0, 131072)
    int s = j >> 6, jj = j & 63;
    float inv = powf(10000.0f, -(float)(2 * jj) * (1.0f / 128.0f));
    float ang = (float)s * inv;
    float sv, cv;
    sincosf(ang, &sv, &cv);
    cosT[j] = cv;
    sinT[j] = sv;
    return;
  }
  const float* s;
  unsigned short* d;
  int off;
  if (i < 2097152) {
    s = x; d = xb; off = i;
  } else {
    int j = i - 2097152;
    int t = j >> 20;
    off = j & 1048575;
    s = (t == 0) ? wq : (t == 1) ? wk : (t == 2) ? wv : wo;
    d = wb + (size_t)t * 4194304;
  }
  float4 v = ((const float4*)s)[off];
  uint2 o;
  o.x = (unsigned int)f_to_bf(v.x) | ((unsigned int)f_to_bf(v.y) << 16);
  o.y = (unsigned int)f_to_bf(v.z) | ((unsigned int)f_to_bf(v.w) << 16);
  ((uint2*)d)[off] = o;
}

// ---------------- merged QKV GEMM (128x128, BK=64, counted-vmcnt dbuf) ------
// C = x[4096,2048] * W[6144,2048]^T, W = [wq; wk; wv] contiguous.
// grid (32, 48): bn>>4 selects sector 0=Q(plain), 1=K(rope), 2=V(->Vt).
// 128-B LDS rows, read swizzle byte^=((row&7)<<4); pre-swizzled gload source.
__global__ __launch_bounds__(256, 2) void qkv_gemm(const unsigned short* __restrict__ A,
                                                   const unsigned short* __restrict__ W,
                                                   unsigned short* __restrict__ Qb,
                                                   unsigned short* __restrict__ Kb,
                                                   unsigned short* __restrict__ Vtb,
                                                   const float* __restrict__ cosT,
                                                   const float* __restrict__ sinT) {
  __shared__ unsigned short sA[2][128 * 64];  // 2 x 16 KB
  __shared__ unsigned short sB[2][128 * 64];  // 2 x 16 KB
  const int K = 2048, N = 2048;
  const int tid = threadIdx.x;
  const int l = tid & 63, wv = tid >> 6;
  const int lane15 = l & 15, lhi = l >> 4;
  const int wm = wv >> 1, wn = wv & 1;
  const int bm = blockIdx.x, bn = blockIdx.y;
  const int sector = bn >> 4, bnl = bn & 15;

  // staging: per thread 4 A-chunks + 4 B-chunks of 16B per tile (8 loads)
  const int srow = tid >> 3;                 // 0..31 -> x4 rows of 32
  const int colD = (tid & 7) << 4;
  const unsigned short* aSrc[4];
  const unsigned short* bSrc[4];
  unsigned int lofs[4];
#pragma unroll
  for (int i = 0; i < 4; i++) {
    int row = i * 32 + srow;
    int cS = colD ^ ((row & 7) << 4);
    aSrc[i] = A + (size_t)(bm * 128 + row) * K + (cS >> 1);
    bSrc[i] = W + (size_t)(bn * 128 + row) * K + (cS >> 1);
    lofs[i] = row * 128 + colD;
  }

  f32x4 acc[4][4];
  const f32x4 zero = {0.f, 0.f, 0.f, 0.f};
#pragma unroll
  for (int i = 0; i < 4; i++)
#pragma unroll
    for (int j = 0; j < 4; j++) acc[i][j] = zero;

  auto stage = [&](int slot) {
#pragma unroll
    for (int i = 0; i < 4; i++) {
      async16(aSrc[i], (char*)&sA[slot][0] + lofs[i]); aSrc[i] += 64;
      async16(bSrc[i], (char*)&sB[slot][0] + lofs[i]); bSrc[i] += 64;
    }
  };
  auto compute = [&](int slot) {
    const char* sAc = (const char*)&sA[slot][0];
    const char* sBc = (const char*)&sB[slot][0];
#pragma unroll
    for (int h = 0; h < 2; h++) {
      bf16x8 af[4], bfr[4];
#pragma unroll
      for (int i = 0; i < 4; i++) {
        int row = wm * 64 + i * 16 + lane15;
        af[i] = *(const bf16x8*)(sAc + row * 128 +
                                 ((h * 64 + lhi * 16) ^ ((row & 7) << 4)));
      }
#pragma unroll
      for (int j = 0; j < 4; j++) {
        int row = wn * 64 + j * 16 + lane15;
        bfr[j] = *(const bf16x8*)(sBc + row * 128 +
                                  ((h * 64 + lhi * 16) ^ ((row & 7) << 4)));
      }
      __builtin_amdgcn_s_setprio(1);
#pragma unroll
      for (int i = 0; i < 4; i++)
#pragma unroll
        for (int j = 0; j < 4; j++)
          acc[i][j] = __builtin_amdgcn_mfma_f32_16x16x32_bf16(af[i], bfr[j], acc[i][j], 0, 0, 0);
      __builtin_amdgcn_s_setprio(0);
    }
  };

  // prologue: stage tiles 0,1 (16 loads in flight)
  stage(0);
  stage(1);

  for (int t = 0; t < 30; ++t) {
    asm volatile("s_waitcnt vmcnt(8)" ::: "memory");  // tile t landed
    __builtin_amdgcn_s_barrier();
    compute(t & 1);
    __builtin_amdgcn_s_barrier();  // all waves done reading slot t&1
    stage(t & 1);                  // tile t+2 -> slot t&1
  }
  asm volatile("s_waitcnt vmcnt(8)" ::: "memory");
  __builtin_amdgcn_s_barrier();
  compute(0);  // t = 30
  asm volatile("s_waitcnt vmcnt(0)" ::: "memory");
  __builtin_amdgcn_s_barrier();
  compute(1);  // t = 31

  // epilogue: C/D layout col=lane&15, row=(lane>>4)*4+r
#pragma unroll
  for (int i = 0; i < 4; i++) {
    int m0 = bm * 128 + wm * 64 + i * 16 + lhi * 4;
#pragma unroll
    for (int j = 0; j < 4; j++) {
      int n = bnl * 128 + wn * 64 + j * 16 + lane15;
      if (sector == 0) {
#pragma unroll
        for (int r = 0; r < 4; r++) Qb[(size_t)(m0 + r) * N + n] = f_to_bf(acc[i][j][r]);
      } else if (sector == 1) {  // K + rope
        int s0 = m0 & (S_ - 1);
        int jp = (n & (HD_ - 1)) >> 1;
        int odd = n & 1;
#pragma unroll
        for (int r = 0; r < 4; r++) {
          float own = acc[i][j][r];
          float prt = __shfl_xor(own, 1);
          float c = cosT[(s0 + r) * 64 + jp];
          float sn = sinT[(s0 + r) * 64 + jp];
          float outv = odd ? fmaf(prt, sn, own * c) : own * c - prt * sn;
          Kb[(size_t)(m0 + r) * N + n] = f_to_bf(outv);
        }
      } else {  // V -> Vt[b*2048 + n][s], 4 consecutive s packed
        int s0 = m0 & (S_ - 1);
        size_t row = (size_t)((m0 >> 11) * D_ + n);
        uint2 st;
        st.x = (unsigned int)f_to_bf(acc[i][j][0]) | ((unsigned int)f_to_bf(acc[i][j][1]) << 16);
        st.y = (unsigned int)f_to_bf(acc[i][j][2]) | ((unsigned int)f_to_bf(acc[i][j][3]) << 16);
        *(uint2*)(Vtb + row * S_ + s0) = st;
      }
    }
  }
}

// ---------------- output GEMM (counted-vmcnt): f32 out ----------------------
__global__ __launch_bounds__(256, 2) void gemm_out(const unsigned short* __restrict__ A,
                                                   const unsigned short* __restrict__ Bm,
                                                   float* __restrict__ Cf) {
  __shared__ unsigned short sA[2][128 * 64];
  __shared__ unsigned short sB[2][128 * 64];
  const int K = 2048, N = 2048;
  const int tid = threadIdx.x;
  const int l = tid & 63, wv = tid >> 6;
  const int lane15 = l & 15, lhi = l >> 4;
  const int wm = wv >> 1, wn = wv & 1;
  const int bm = blockIdx.x, bn = blockIdx.y;

  const int srow = tid >> 3;
  const int colD = (tid & 7) << 4;
  const unsigned short* aSrc[4];
  const unsigned short* bSrc[4];
  unsigned int lofs[4];
#pragma unroll
  for (int i = 0; i < 4; i++) {
    int row = i * 32 + srow;
    int cS = colD ^ ((row & 7) << 4);
    aSrc[i] = A + (size_t)(bm * 128 + row) * K + (cS >> 1);
    bSrc[i] = Bm + (size_t)(bn * 128 + row) * K + (cS >> 1);
    lofs[i] = row * 128 + colD;
  }

  f32x4 acc[4][4];
  const f32x4 zero = {0.f, 0.f, 0.f, 0.f};
#pragma unroll
  for (int i = 0; i < 4; i++)
#pragma unroll
    for (int j = 0; j < 4; j++) acc[i][j] = zero;

  auto stage = [&](int slot) {
#pragma unroll
    for (int i = 0; i < 4; i++) {
      async16(aSrc[i], (char*)&sA[slot][0] + lofs[i]); aSrc[i] += 64;
      async16(bSrc[i], (char*)&sB[slot][0] + lofs[i]); bSrc[i] += 64;
    }
  };
  auto compute = [&](int slot) {
    const char* sAc = (const char*)&sA[slot][0];
    const char* sBc = (const char*)&sB[slot][0];
#pragma unroll
    for (int h = 0; h < 2; h++) {
      bf16x8 af[4], bfr[4];
#pragma unroll
      for (int i = 0; i < 4; i++) {
        int row = wm * 64 + i * 16 + lane15;
        af[i] = *(const bf16x8*)(sAc + row * 128 +
                                 ((h * 64 + lhi * 16) ^ ((row & 7) << 4)));
      }
#pragma unroll
      for (int j = 0; j < 4; j++) {
        int row = wn * 64 + j * 16 + lane15;
        bfr[j] = *(const bf16x8*)(sBc + row * 128 +
                                  ((h * 64 + lhi * 16) ^ ((row & 7) << 4)));
      }
      __builtin_amdgcn_s_setprio(1);
#pragma unroll
      for (int i = 0; i < 4; i++)
#pragma unroll
        for (int j = 0; j < 4; j++)
          acc[i][j] = __builtin_amdgcn_mfma_f32_16x16x32_bf16(af[i], bfr[j], acc[i][j], 0, 0, 0);
      __builtin_amdgcn_s_setprio(0);
    }
  };

  stage(0);
  stage(1);
  for (int t = 0; t < 30; ++t) {
    asm volatile("s_waitcnt vmcnt(8)" ::: "memory");
    __builtin_amdgcn_s_barrier();
    compute(t & 1);
    __builtin_amdgcn_s_barrier();
    stage(t & 1);
  }
  asm volatile("s_waitcnt vmcnt(8)" ::: "memory");
  __builtin_amdgcn_s_barrier();
  compute(0);
  asm volatile("s_waitcnt vmcnt(0)" ::: "memory");
  __builtin_amdgcn_s_barrier();
  compute(1);

#pragma unroll
  for (int i = 0; i < 4; i++) {
    int m0 = bm * 128 + wm * 64 + i * 16 + lhi * 4;
#pragma unroll
    for (int j = 0; j < 4; j++) {
      int n = bn * 128 + wn * 64 + j * 16 + lane15;
#pragma unroll
      for (int r = 0; r < 4; r++) Cf[(size_t)(m0 + r) * N + n] = acc[i][j][r];
    }
  }
}

// ---------------- flash attention (r11-14 syncthreads-dbuf structure) -------
// grid (8, 32): 256 blocks of 512 threads = 1 block/CU.
// XCD swizzle: blockIdx.x owns bh in [bx*4, bx*4+4) (4 MB KV = its L2).
// KVBLK=128 (16 k-tiles); 8 waves x QBLK=32; waves 0-3 stage K, 4-7 stage V.
// Scores in log2-units; P in registers (cvt_pk + permlane swaps).
__global__ __launch_bounds__(512, 2) void attn_kernel(const unsigned short* __restrict__ Q,
                                                      const unsigned short* __restrict__ K,
                                                      const unsigned short* __restrict__ Vt,
                                                      unsigned short* __restrict__ ctx,
                                                      const float* __restrict__ cosT,
                                                      const float* __restrict__ sinT) {
  __shared__ unsigned short sK[2][KVB * 128];  // [k][d], 256B rows, 32 KB each
  __shared__ unsigned short sV[2][128 * KVB];  // [d][s], 256B rows, 32 KB each
  const int tid = threadIdx.x, l = tid & 63, w = tid >> 6;
  const int lane15 = l & 15, lhi = l >> 4;
  const int bh = blockIdx.x * 4 + (blockIdx.y >> 3);
  const int qt = blockIdx.y & 7;
  const int b = bh >> 4, h = bh & 15;
  const int q0 = qt * 256;
  const unsigned short* Kg = K + ((size_t)(b * S_)) * D_ + h * HD_;
  const unsigned short* Vg = Vt + ((size_t)bh * HD_) * S_;
  const float qscale = 0.08838834764831845f * 1.44269504f;  // scale * log2(e)
  const float THR = 11.5415603f;                            // 8 * log2(e)

  const unsigned short* gp[8];
  unsigned int lofs[8];
  size_t gstep;
  if (w < 4) {
#pragma unroll
    for (int i = 0; i < 8; i++) {
      int row = w * 32 + i * 4 + (l >> 4);
      int colD = (l & 15) << 4;
      int colS = colD ^ ((row & 7) << 4);
      gp[i] = Kg + (size_t)row * D_ + (colS >> 1);
      lofs[i] = row * 256 + colD;
    }
    gstep = (size_t)KVB * D_;
  } else {
#pragma unroll
    for (int i = 0; i < 8; i++) {
      int row = (w - 4) * 32 + i * 4 + (l >> 4);
      int colD = (l & 15) << 4;
      int colS = colD ^ ((row & 7) << 4);
      gp[i] = Vg + (size_t)row * S_ + (colS >> 1);
      lofs[i] = row * 256 + colD;
    }
    gstep = KVB;
  }

  // Q load + RoPE + qscale (once per block; pairs in-lane)
  bf16x8 qf[2][4];
#pragma unroll
  for (int s = 0; s < 2; s++) {
    int s_q = q0 + w * 32 + s * 16 + lane15;
    const unsigned short* Qrow = Q + ((size_t)(b * S_ + s_q)) * D_ + h * HD_;
#pragma unroll
    for (int kc = 0; kc < 4; kc++) {
      int d0 = kc * 32 + lhi * 8;
      uint4 raw = *(const uint4*)(Qrow + d0);
      float4 cv = *(const float4*)(cosT + (size_t)s_q * 64 + (d0 >> 1));
      float4 sv = *(const float4*)(sinT + (size_t)s_q * 64 + (d0 >> 1));
      unsigned int u[4] = {raw.x, raw.y, raw.z, raw.w};
      float cc[4] = {cv.x, cv.y, cv.z, cv.w};
      float ss[4] = {sv.x, sv.y, sv.z, sv.w};
      unsigned int o[4];
#pragma unroll
      for (int p = 0; p < 4; p++) {
        float re = bf_to_f((unsigned short)(u[p] & 0xffffu));
        float im = bf_to_f((unsigned short)(u[p] >> 16));
        float orr = (re * cc[p] - im * ss[p]) * qscale;
        float oi = (re * ss[p] + im * cc[p]) * qscale;
        o[p] = (unsigned int)f_to_bf(orr) | ((unsigned int)f_to_bf(oi) << 16);
      }
      union { uint4 u4; bf16x8 v; } cvt;
      cvt.u4.x = o[0]; cvt.u4.y = o[1]; cvt.u4.z = o[2]; cvt.u4.w = o[3];
      qf[s][kc] = cvt.v;
    }
  }

  float mrun[2] = {-1e30f, -1e30f}, lrun[2] = {0.f, 0.f};
  const f32x4 zero = {0.f, 0.f, 0.f, 0.f};
  f32x4 oacc[2][8];
#pragma unroll
  for (int s = 0; s < 2; s++)
#pragma unroll
    for (int nf = 0; nf < 8; nf++) oacc[s][nf] = zero;

  {
    char* base = (w < 4) ? (char*)&sK[0][0] : (char*)&sV[0][0];
#pragma unroll
    for (int i = 0; i < 8; i++) { async16(gp[i], base + lofs[i]); gp[i] += gstep; }
  }

  for (int t = 0; t < S_ / KVB; ++t) {
    const int cur = t & 1;
    __syncthreads();  // drains prev-step loads (had full compute to land)
    if (t < S_ / KVB - 1) {
      char* base = (w < 4) ? (char*)&sK[cur ^ 1][0] : (char*)&sV[cur ^ 1][0];
#pragma unroll
      for (int i = 0; i < 8; i++) { async16(gp[i], base + lofs[i]); gp[i] += gstep; }
    }
    const unsigned short* sKc = sK[cur];
    const unsigned short* sVc = sV[cur];

    f32x4 sacc[2][8];
#pragma unroll
    for (int s = 0; s < 2; s++)
#pragma unroll
      for (int n = 0; n < 8; n++) sacc[s][n] = zero;
    __builtin_amdgcn_s_setprio(1);
#pragma unroll
    for (int n = 0; n < 8; n++) {
      int row = n * 16 + lane15;
#pragma unroll
      for (int kc = 0; kc < 4; kc++) {
        bf16x8 kf = *(const bf16x8*)((const char*)sKc + row * 256 +
                                     ((kc * 64 + lhi * 16) ^ ((row & 7) << 4)));
        sacc[0][n] = __builtin_amdgcn_mfma_f32_16x16x32_bf16(kf, qf[0][kc], sacc[0][n], 0, 0, 0);
        sacc[1][n] = __builtin_amdgcn_mfma_f32_16x16x32_bf16(kf, qf[1][kc], sacc[1][n], 0, 0, 0);
      }
    }
    __builtin_amdgcn_s_setprio(0);

    float pmax[2];
#pragma unroll
    for (int s = 0; s < 2; s++) {
      float mn[8];
#pragma unroll
      for (int n = 0; n < 8; n++)
        mn[n] = fmaxf(fmaxf(sacc[s][n][0], sacc[s][n][1]), fmaxf(sacc[s][n][2], sacc[s][n][3]));
      float pm = fmaxf(fmaxf(fmaxf(mn[0], mn[1]), fmaxf(mn[2], mn[3])),
                       fmaxf(fmaxf(mn[4], mn[5]), fmaxf(mn[6], mn[7])));
      pm = fmaxf(pm, __shfl_xor(pm, 16));
      pm = fmaxf(pm, __shfl_xor(pm, 32));
      pmax[s] = pm;
    }
    if (!__all(fmaxf(pmax[0] - mrun[0], pmax[1] - mrun[1]) <= THR)) {
#pragma unroll
      for (int s = 0; s < 2; s++) {
        float mnew = fmaxf(mrun[s], pmax[s]);
        float alpha = exp2f(mrun[s] - mnew);
        lrun[s] *= alpha;
        float af[4];
#pragma unroll
        for (int r = 0; r < 4; r++) af[r] = __shfl(alpha, lhi * 4 + r);
#pragma unroll
        for (int nf = 0; nf < 8; nf++)
#pragma unroll
          for (int r = 0; r < 4; r++) oacc[s][nf][r] *= af[r];
        mrun[s] = mnew;
      }
    }
    bf16x8 paS[2][4];
#pragma unroll
    for (int s = 0; s < 2; s++) {
      float rs = 0.f;
      unsigned int wlo[8], whi[8];
#pragma unroll
      for (int n = 0; n < 8; n++) {
        float p0 = exp2f(sacc[s][n][0] - mrun[s]);
        float p1 = exp2f(sacc[s][n][1] - mrun[s]);
        float p2 = exp2f(sacc[s][n][2] - mrun[s]);
        float p3 = exp2f(sacc[s][n][3] - mrun[s]);
        rs += (p0 + p1) + (p2 + p3);
        wlo[n] = cvt_pk_bf16(p0, p1);
        whi[n] = cvt_pk_bf16(p2, p3);
      }
      rs += __shfl_xor(rs, 16);
      rs += __shfl_xor(rs, 32);
      lrun[s] += rs;
#pragma unroll
      for (int kc = 0; kc < 4; kc++) {
        unsigned int A = wlo[2 * kc], Bw = whi[2 * kc];
        unsigned int C = wlo[2 * kc + 1], Dw = whi[2 * kc + 1];
        asm("v_permlane32_swap_b32 %0, %1" : "+v"(A), "+v"(C));
        asm("v_permlane16_swap_b32 %0, %1" : "+v"(A), "+v"(C));
        asm("v_permlane32_swap_b32 %0, %1" : "+v"(Bw), "+v"(Dw));
        asm("v_permlane16_swap_b32 %0, %1" : "+v"(Bw), "+v"(Dw));
        union { uint4 u4; bf16x8 v; } pk;
        pk.u4.x = A; pk.u4.y = Bw; pk.u4.z = C; pk.u4.w = Dw;
        paS[s][kc] = pk.v;
      }
    }

    __builtin_amdgcn_s_setprio(1);
#pragma unroll
    for (int nf = 0; nf < 8; nf++) {
      int row = nf * 16 + lane15;
#pragma unroll
      for (int kc = 0; kc < 4; kc++) {
        bf16x8 vf = *(const bf16x8*)((const char*)sVc + row * 256 +
                                     ((kc * 64 + lhi * 16) ^ ((row & 7) << 4)));
        oacc[0][nf] = __builtin_amdgcn_mfma_f32_16x16x32_bf16(paS[0][kc], vf, oacc[0][nf], 0, 0, 0);
        oacc[1][nf] = __builtin_amdgcn_mfma_f32_16x16x32_bf16(paS[1][kc], vf, oacc[1][nf], 0, 0, 0);
      }
    }
    __builtin_amdgcn_s_setprio(0);
  }

#pragma unroll
  for (int s = 0; s < 2; s++) {
    float inv = 1.0f / lrun[s];
    float invr[4];
#pragma unroll
    for (int r = 0; r < 4; r++) invr[r] = __shfl(inv, lhi * 4 + r);
    unsigned short* Og = ctx + ((size_t)(b * S_ + q0 + w * 32 + s * 16)) * D_ + h * HD_;
#pragma unroll
    for (int r = 0; r < 4; r++) {
      int qrow = lhi * 4 + r;
#pragma unroll
      for (int nf = 0; nf < 8; nf++)
        Og[(size_t)qrow * D_ + nf * 16 + lane15] = f_to_bf(oacc[s][nf][r] * invr[r]);
    }
  }
}

// ---------------- launcher ----------------
extern "C" void kernel_launch(void* const* d_in, const int* in_sizes, int n_in,
                              void* d_out, int out_size, void* d_ws, size_t ws_size,
                              hipStream_t stream) {
  (void)in_sizes; (void)n_in; (void)out_size; (void)ws_size;
  const float* x = (const float*)d_in[0];
  const float* wq = (const float*)d_in[1];
  const float* wk = (const float*)d_in[2];
  const float* wv = (const float*)d_in[3];
  const float* wo = (const float*)d_in[4];
  float* out = (float*)d_out;

  char* ws = (char*)d_ws;
  const size_t MB = 1024 * 1024;
  unsigned short* xb  = (unsigned short*)(ws + 0 * MB);    // 16 MB; later aliased as ctx
  unsigned short* wqb = (unsigned short*)(ws + 16 * MB);   // W[6144+2048][2048] contiguous
  unsigned short* wob = (unsigned short*)(ws + 40 * MB);
  unsigned short* Qb  = (unsigned short*)(ws + 48 * MB);   // 16 MB
  unsigned short* Kb  = (unsigned short*)(ws + 64 * MB);   // 16 MB
  unsigned short* Vtb = (unsigned short*)(ws + 80 * MB);   // 16 MB
  float* cosT = (float*)(ws + 96 * MB);                    // 0.5 MB
  float* sinT = (float*)(ws + 96 * MB + 524288);           // 0.5 MB
  unsigned short* ctxb = xb;  // x_bf16 dead after QKV GEMM

  const int M = B_ * S_;  // 4096

  conv_all<<<25088, 256, 0, stream>>>(x, wq, wk, wv, wo, xb, wqb, cosT, sinT);

  qkv_gemm<<<dim3(M / 128, 48), 256, 0, stream>>>(xb, wqb, Qb, Kb, Vtb, cosT, sinT);

  attn_kernel<<<dim3(8, 32), 512, 0, stream>>>(Qb, Kb, Vtb, ctxb, cosT, sinT);

  gemm_out<<<dim3(M / 128, D_ / 128), 256, 0, stream>>>(ctxb, wob, out);
}